// Round 12
// baseline (1256.326 us; speedup 1.0000x reference)
//
#include <hip/hip_runtime.h>

#define NN 100000
#define EE 1600000
#define HD 64
#define OCD 16
#define NBUCK 391          // ceil(NN/256)
#define CAP 5888           // per-bucket edge capacity incl. align slack
#define BN_EPS 1e-5f

typedef unsigned short u16;
typedef unsigned long long u64;
typedef __attribute__((ext_vector_type(8))) short short8v;  // 8 bf16 (4 VGPR)
typedef __attribute__((ext_vector_type(4))) float f32x4;

union f32u32 { float f; unsigned int u; };

__device__ __forceinline__ float bflo(unsigned int u) {
    f32u32 c; c.u = u << 16; return c.f;
}
__device__ __forceinline__ float bfhi(unsigned int u) {
    f32u32 c; c.u = u & 0xffff0000u; return c.f;
}
__device__ __forceinline__ float bf2f(u16 u) {
    f32u32 c; c.u = (unsigned int)u << 16; return c.f;
}
__device__ __forceinline__ u16 f2bf(float f) {
    f32u32 c; c.f = f;
    unsigned int r = 0x7fffu + ((c.u >> 16) & 1u);   // RNE
    return (u16)((c.u + r) >> 16);
}

// ================================================================ bucket pass A (dst)
__global__ __launch_bounds__(256) void bucketA_kernel(
        const int* __restrict__ src, const int* __restrict__ dst,
        int* __restrict__ gcd, u64* __restrict__ bregion) {
    __shared__ int lh[NBUCK], lbase[NBUCK], lcur[NBUCK];
    int t = threadIdx.x;
    int ebase = blockIdx.x * 4096;

    for (int i = t; i < NBUCK; i += 256) lh[i] = 0;
    __syncthreads();

    int es[16], ed[16];
    #pragma unroll
    for (int j = 0; j < 16; ++j) {
        int e = ebase + j * 256 + t;
        if (e < EE) {
            es[j] = src[e]; ed[j] = dst[e];
            atomicAdd(&lh[ed[j] >> 8], 1);
        } else { es[j] = -1; ed[j] = 0; }
    }
    __syncthreads();
    for (int i = t; i < NBUCK; i += 256) {
        int c = lh[i];
        lbase[i] = (c > 0) ? atomicAdd(&gcd[i * 16], c) : 0;
        lcur[i] = 0;
    }
    __syncthreads();
    #pragma unroll
    for (int j = 0; j < 16; ++j) {
        if (es[j] >= 0) {
            int b = ed[j] >> 8;
            int r = atomicAdd(&lcur[b], 1);
            int pos = lbase[b] + r;
            if (pos < CAP)
                bregion[(size_t)b * CAP + pos] =
                    (u64)(unsigned int)es[j] | ((u64)(unsigned int)ed[j] << 32);
        }
    }
}

// bucket pass A2 (src, for out-degree)
__global__ __launch_bounds__(256) void bucketA2_kernel(
        const int* __restrict__ src,
        int* __restrict__ gcs, int* __restrict__ sregion) {
    __shared__ int lh[NBUCK], lbase[NBUCK], lcur[NBUCK];
    int t = threadIdx.x;
    int ebase = blockIdx.x * 4096;

    for (int i = t; i < NBUCK; i += 256) lh[i] = 0;
    __syncthreads();

    int es[16];
    #pragma unroll
    for (int j = 0; j < 16; ++j) {
        int e = ebase + j * 256 + t;
        if (e < EE) {
            es[j] = src[e];
            atomicAdd(&lh[es[j] >> 8], 1);
        } else es[j] = -1;
    }
    __syncthreads();
    for (int i = t; i < NBUCK; i += 256) {
        int c = lh[i];
        lbase[i] = (c > 0) ? atomicAdd(&gcs[i * 16], c) : 0;
        lcur[i] = 0;
    }
    __syncthreads();
    #pragma unroll
    for (int j = 0; j < 16; ++j) {
        if (es[j] >= 0) {
            int b = es[j] >> 8;
            int r = atomicAdd(&lcur[b], 1);
            int pos = lbase[b] + r;
            if (pos < CAP)
                sregion[(size_t)b * CAP + pos] = es[j];
        }
    }
}

// pass B: per dst-bucket CSR, row starts 4-aligned
__global__ __launch_bounds__(256) void bucketB_kernel(
        const int* __restrict__ gcd, const u64* __restrict__ bregion,
        int* __restrict__ rstart, int* __restrict__ deg,
        int* __restrict__ colp) {
    __shared__ int lh[256], lsc[256], lcur[256];
    int b = blockIdx.x, t = threadIdx.x;
    int cnt = min(gcd[b * 16], CAP - 768);
    size_t base = (size_t)b * CAP;

    lh[t] = 0;
    __syncthreads();
    for (int i = t; i < cnt; i += 256) {
        int d = (int)(bregion[base + i] >> 32);
        atomicAdd(&lh[d & 255], 1);
    }
    __syncthreads();
    int deg4 = (lh[t] + 3) & ~3;
    lsc[t] = deg4;
    __syncthreads();
    for (int o = 1; o < 256; o <<= 1) {
        int v = (t >= o) ? lsc[t - o] : 0;
        __syncthreads();
        lsc[t] += v;
        __syncthreads();
    }
    int excl = lsc[t] - deg4;
    int node = b * 256 + t;
    if (node < NN) {
        rstart[node] = (int)base + excl;
        deg[node] = lh[t];
    }
    lcur[t] = excl;
    __syncthreads();
    for (int i = t; i < cnt; i += 256) {
        u64 pair = bregion[base + i];
        int s = (int)(unsigned int)(pair & 0xffffffffu);
        int dl = ((int)(pair >> 32)) & 255;
        int p = atomicAdd(&lcur[dl], 1);
        colp[base + p] = s;
    }
}

// per src-bucket: out-degree -> cs
__global__ __launch_bounds__(256) void bucketB2_kernel(
        const int* __restrict__ gcs, const int* __restrict__ sregion,
        int* __restrict__ cs) {
    __shared__ int lh[256];
    int b = blockIdx.x, t = threadIdx.x;
    int cnt = min(gcs[b * 16], CAP);
    size_t base = (size_t)b * CAP;

    lh[t] = 0;
    __syncthreads();
    for (int i = t; i < cnt; i += 256)
        atomicAdd(&lh[sregion[base + i] & 255], 1);
    __syncthreads();
    int node = b * 256 + t;
    if (node < NN) cs[node] = lh[t];
}

__global__ void dinv_kernel(const int* __restrict__ cs, float* __restrict__ dinv,
                            float* __restrict__ ndsq, float* __restrict__ sdeg) {
    int i = blockIdx.x * 256 + threadIdx.x;
    if (i < NN) {
        int d = cs[i];
        float di = (d > 0) ? rsqrtf((float)d) : 0.0f;
        dinv[i] = di;
        ndsq[i] = -di * di;
        sdeg[i] = (d > 0) ? sqrtf((float)d) : 0.0f;
    }
}

// ================================================================ weight fold + MFMA-fragment repack
__global__ void fold_kernel(const float* __restrict__ W, const float* __restrict__ bc,
                            const float* __restrict__ g, const float* __restrict__ be,
                            const float* __restrict__ rm, const float* __restrict__ rv,
                            u16* __restrict__ Wfrag, float* __restrict__ biasf) {
    int idx = blockIdx.x * 256 + threadIdx.x;
    if (idx >= 16384) return;
    int km = idx >> 12, r = idx & 4095, i = r >> 6, h = r & 63;
    float sc = g[h] * rsqrtf(rv[h] + BN_EPS);
    int e = i * 64 + h;
    float wv;
    if      (km == 0) wv = (W[e] - W[8192 + e]) * sc;
    else if (km == 1) wv = (W[4096 + e] - 3.0f * W[12288 + e]) * sc;
    else if (km == 2) wv = 2.0f * W[8192 + e] * sc;
    else              wv = 4.0f * W[12288 + e] * sc;
    u16 hi = f2bf(wv);
    u16 lo = f2bf(wv - bf2f(hi));
    int lane = (((i & 31) >> 3) << 4) | (h & 15);
    int base = (km * 2) * 4096 + (i >> 5) * 2048 + (h >> 4) * 512 + lane * 8 + (i & 7);
    Wfrag[base] = hi;
    Wfrag[base + 4096] = lo;
    if (idx < 64)
        biasf[idx] = (bc[idx] - rm[idx]) * g[idx] * rsqrtf(rv[idx] + BN_EPS) + be[idx];
}

// ================================================================ x -> Xhi/Xlo (row-major) + P0 (sliced [4][NN][16])
__global__ void scale0_kernel(const float* __restrict__ x, const float* __restrict__ dinv,
                              u16* __restrict__ Xhi, u16* __restrict__ Xlo,
                              u16* __restrict__ P0) {
    int idx = blockIdx.x * 256 + threadIdx.x;   // one (slice, node), slice-major
    if (idx >= 4 * NN) return;
    int s = idx / NN, n = idx - s * NN;
    float di = dinv[n];
    const float4* xr = (const float4*)(x + (size_t)n * HD + s * 16);
    u16 hi[16], lo[16], p[16];
    #pragma unroll
    for (int q = 0; q < 4; ++q) {
        float4 v = xr[q];
        float vv[4] = {v.x, v.y, v.z, v.w};
        #pragma unroll
        for (int j = 0; j < 4; ++j) {
            int f = q * 4 + j;
            hi[f] = f2bf(vv[j]);
            lo[f] = f2bf(vv[j] - bf2f(hi[f]));
            p[f]  = f2bf(di * vv[j]);
        }
    }
    uint4* xh = (uint4*)(Xhi + (size_t)n * HD + s * 16);
    uint4* xl = (uint4*)(Xlo + (size_t)n * HD + s * 16);
    uint4* pp = (uint4*)(P0 + ((size_t)s * NN + n) * 16);
    xh[0] = ((const uint4*)hi)[0]; xh[1] = ((const uint4*)hi)[1];
    xl[0] = ((const uint4*)lo)[0]; xl[1] = ((const uint4*)lo)[1];
    pp[0] = ((const uint4*)p)[0];  pp[1] = ((const uint4*)p)[1];
}

// ================================================================ propagation (XCD-pinned feature slice)
// P layout [4][NN][16]. slice = bid & 3 -> XCD round-robin keeps one 3.2MB
// slice hot per XCD L2. Wave: 16 edge-groups x 4 lanes x 8B = one 32B row/load.
__global__ __launch_bounds__(256) void prop_kernel(
        const u16* __restrict__ Pin, u16* __restrict__ Pout,
        const int* __restrict__ rstart, const int* __restrict__ deg,
        const int* __restrict__ col, const float* __restrict__ ndsq) {
    int bid = blockIdx.x;
    int s = bid & 3;
    int d = (bid >> 2) * 4 + (threadIdx.x >> 6);
    if (d >= NN) return;
    int lane = threadIdx.x & 63;
    int g = lane >> 2;        // 0..15 edge slot
    int l = lane & 3;         // feature quad within slice
    const u16* Ps = Pin + (size_t)s * NN * 16;
    u16* Pd = Pout + (size_t)s * NN * 16;
    int e0 = rstart[d], e1 = e0 + deg[d];

    float a0 = 0.f, a1 = 0.f, a2 = 0.f, a3 = 0.f;
    for (int e = e0 + g; e < e1; e += 16) {
        int sc = col[e];
        uint2 u = *(const uint2*)(Ps + (size_t)sc * 16 + l * 4);
        a0 += bflo(u.x); a1 += bfhi(u.x);
        a2 += bflo(u.y); a3 += bfhi(u.y);
    }
    #pragma unroll
    for (int m = 4; m <= 32; m <<= 1) {
        a0 += __shfl_xor(a0, m);
        a1 += __shfl_xor(a1, m);
        a2 += __shfl_xor(a2, m);
        a3 += __shfl_xor(a3, m);
    }
    if (g == 0) {
        float nd = ndsq[d];
        uint2 o;
        o.x = (unsigned int)f2bf(nd * a0) | ((unsigned int)f2bf(nd * a1) << 16);
        o.y = (unsigned int)f2bf(nd * a2) | ((unsigned int)f2bf(nd * a3) << 16);
        *(uint2*)(Pd + (size_t)d * 16 + l * 4) = o;
    }
}

// ================================================================ MFMA combine (P sliced, X row-major)
template<bool FUSE_HEAD>
__global__ __launch_bounds__(256) void combine_kernel(
        const u16* __restrict__ Xhi, const u16* __restrict__ Xlo,
        const u16* __restrict__ P1, const u16* __restrict__ P2,
        const u16* __restrict__ P3,
        const float* __restrict__ sdeg, const float* __restrict__ dinv,
        const u16* __restrict__ Wfrag, const float* __restrict__ biasf,
        u16* __restrict__ outDhi, u16* __restrict__ outDlo, u16* __restrict__ outP0,
        const float* __restrict__ headW, const float* __restrict__ headB,
        float* __restrict__ out16) {
    int t = threadIdx.x;
    int w = t >> 6;           // m-tile
    int l = t & 63;
    int nbase = blockIdx.x * 64;

    int arow = nbase + w * 16 + (l & 15);
    if (arow > NN - 1) arow = NN - 1;            // tail clamp (stores guarded)
    size_t abase = (size_t)arow * HD;

    f32x4 accX[4], accP[4];
    #pragma unroll
    for (int nt = 0; nt < 4; ++nt) {
        accX[nt] = (f32x4){0.f, 0.f, 0.f, 0.f};
        accP[nt] = (f32x4){0.f, 0.f, 0.f, 0.f};
    }

    #pragma unroll
    for (int ks = 0; ks < 2; ++ks) {
        int fb = ks * 32 + (l >> 4) * 8;         // k-fragment feature base
        size_t ao = abase + fb;                  // row-major X
        size_t po = ((size_t)(fb >> 4) * NN + arow) * 16 + (fb & 15);  // sliced P
        short8v aXhi = *(const short8v*)(Xhi + ao);
        short8v aXlo = *(const short8v*)(Xlo + ao);
        short8v aP1  = *(const short8v*)(P1 + po);
        short8v aP2  = *(const short8v*)(P2 + po);
        short8v aP3  = *(const short8v*)(P3 + po);
        #pragma unroll
        for (int nt = 0; nt < 4; ++nt) {
            const u16* wb = Wfrag + ks * 2048 + nt * 512 + l * 8;
            short8v b0h = *(const short8v*)(wb);            // km0 hi
            short8v b0l = *(const short8v*)(wb + 4096);     // km0 lo
            short8v b1h = *(const short8v*)(wb + 8192);
            short8v b1l = *(const short8v*)(wb + 12288);
            short8v b2h = *(const short8v*)(wb + 16384);
            short8v b2l = *(const short8v*)(wb + 20480);
            short8v b3h = *(const short8v*)(wb + 24576);
            short8v b3l = *(const short8v*)(wb + 28672);
            accX[nt] = __builtin_amdgcn_mfma_f32_16x16x32_bf16(aXhi, b0h, accX[nt], 0, 0, 0);
            accX[nt] = __builtin_amdgcn_mfma_f32_16x16x32_bf16(aXlo, b0h, accX[nt], 0, 0, 0);
            accX[nt] = __builtin_amdgcn_mfma_f32_16x16x32_bf16(aXhi, b0l, accX[nt], 0, 0, 0);
            accP[nt] = __builtin_amdgcn_mfma_f32_16x16x32_bf16(aP1,  b1h, accP[nt], 0, 0, 0);
            accP[nt] = __builtin_amdgcn_mfma_f32_16x16x32_bf16(aP1,  b1l, accP[nt], 0, 0, 0);
            accP[nt] = __builtin_amdgcn_mfma_f32_16x16x32_bf16(aP2,  b2h, accP[nt], 0, 0, 0);
            accP[nt] = __builtin_amdgcn_mfma_f32_16x16x32_bf16(aP2,  b2l, accP[nt], 0, 0, 0);
            accP[nt] = __builtin_amdgcn_mfma_f32_16x16x32_bf16(aP3,  b3h, accP[nt], 0, 0, 0);
            accP[nt] = __builtin_amdgcn_mfma_f32_16x16x32_bf16(aP3,  b3l, accP[nt], 0, 0, 0);
        }
    }

    // epilogue: C/D layout col=lane&15, row=(lane>>4)*4+reg  [m89 verified]
    int col = l & 15;
    int rbase = w * 16 + (l >> 4) * 4;

    if (!FUSE_HEAD) {
        #pragma unroll
        for (int nt = 0; nt < 4; ++nt) {
            int h = nt * 16 + col;
            float bi = biasf[h];
            #pragma unroll
            for (int reg = 0; reg < 4; ++reg) {
                int node = nbase + rbase + reg;
                int nodeL = node > NN - 1 ? NN - 1 : node;
                float val = accX[nt][reg] + sdeg[nodeL] * accP[nt][reg] + bi;
                val = fmaxf(val, 0.f);
                if (node < NN) {
                    u16 hi = f2bf(val);
                    size_t o = (size_t)node * HD + h;
                    outDhi[o] = hi;
                    outDlo[o] = f2bf(val - bf2f(hi));
                    // sliced P0: slice = nt, offset = col
                    outP0[((size_t)nt * NN + node) * 16 + col] = f2bf(dinv[nodeL] * val);
                }
            }
        }
    } else {
        __shared__ float Tl[64][68];
        __shared__ float Wl[HD * OCD];
        #pragma unroll
        for (int nt = 0; nt < 4; ++nt) {
            int h = nt * 16 + col;
            float bi = biasf[h];
            #pragma unroll
            for (int reg = 0; reg < 4; ++reg) {
                int node = nbase + rbase + reg;
                int nodeL = node > NN - 1 ? NN - 1 : node;
                float val = accX[nt][reg] + sdeg[nodeL] * accP[nt][reg] + bi;
                Tl[rbase + reg][h] = fmaxf(val, 0.f);
            }
        }
        ((float4*)Wl)[t & 255] = ((const float4*)headW)[t & 255];  // 1024 floats
        __syncthreads();

        int n = t >> 2;
        int oc0 = (t & 3) * 4;
        float4 o;
        o.x = headB[oc0]; o.y = headB[oc0 + 1]; o.z = headB[oc0 + 2]; o.w = headB[oc0 + 3];
        #pragma unroll 8
        for (int i = 0; i < 64; ++i) {
            float tv = Tl[n][i];
            const float* wr = &Wl[i * OCD + oc0];
            o.x = fmaf(tv, wr[0], o.x);
            o.y = fmaf(tv, wr[1], o.y);
            o.z = fmaf(tv, wr[2], o.z);
            o.w = fmaf(tv, wr[3], o.w);
        }
        int nn = nbase + n;
        if (nn < NN) *(float4*)(&out16[(size_t)nn * OCD + oc0]) = o;
    }
}

// ================================================================ launch
static inline size_t al256(size_t x) { return (x + 255) & ~(size_t)255; }

extern "C" void kernel_launch(void* const* d_in, const int* in_sizes, int n_in,
                              void* d_out, int out_size, void* d_ws, size_t ws_size,
                              hipStream_t stream) {
    const float* x     = (const float*)d_in[0];
    const int*   ei    = (const int*)  d_in[1];
    const float* W1    = (const float*)d_in[2];
    const float* bc1   = (const float*)d_in[3];
    const float* W2    = (const float*)d_in[4];
    const float* bc2   = (const float*)d_in[5];
    const float* W3    = (const float*)d_in[6];
    const float* bc3   = (const float*)d_in[7];
    const float* g1  = (const float*)d_in[8],  *be1 = (const float*)d_in[9];
    const float* rm1 = (const float*)d_in[10], *rv1 = (const float*)d_in[11];
    const float* g2  = (const float*)d_in[12], *be2 = (const float*)d_in[13];
    const float* rm2 = (const float*)d_in[14], *rv2 = (const float*)d_in[15];
    const float* g3  = (const float*)d_in[16], *be3 = (const float*)d_in[17];
    const float* rm3 = (const float*)d_in[18], *rv3 = (const float*)d_in[19];
    const float* headW = (const float*)d_in[20];
    const float* headB = (const float*)d_in[21];

    const int* src = ei;
    const int* dst = ei + EE;

    char* w = (char*)d_ws;
    size_t off = 0;
    auto take = [&](size_t bytes) { char* p = w + off; off += al256(bytes); return p; };
    float* dinv   = (float*)take(NN * 4);
    float* ndsq   = (float*)take(NN * 4);
    float* sdeg   = (float*)take(NN * 4);
    int*   cs     = (int*)  take(NN * 4);
    int*   deg    = (int*)  take(NN * 4);
    int*   rstart = (int*)  take(NN * 4);
    int*   gc     = (int*)  take(2 * NBUCK * 16 * 4);        // gcd | gcs contiguous
    int*   gcd    = gc;
    int*   gcs    = gc + NBUCK * 16;
    u64*   bregion= (u64*)  take((size_t)NBUCK * CAP * 8);   // 18.4 MB
    int*   sregion= (int*)  take((size_t)NBUCK * CAP * 4);   //  9.2 MB
    int*   colp   = (int*)  take((size_t)NBUCK * CAP * 4);   //  9.2 MB
    u16*   Wfrag1 = (u16*)  take(32768 * 2);                 // 64 KB each
    u16*   Wfrag2 = (u16*)  take(32768 * 2);
    u16*   Wfrag3 = (u16*)  take(32768 * 2);
    float* bf1    = (float*)take(64 * 4);
    float* bf2    = (float*)take(64 * 4);
    float* bf3    = (float*)take(64 * 4);
    const size_t NH = (size_t)NN * HD;
    u16* Xhi = (u16*)take(NH * 2);
    u16* Xlo = (u16*)take(NH * 2);
    u16* Yhi = (u16*)take(NH * 2);
    u16* Ylo = (u16*)take(NH * 2);
    u16* P0  = (u16*)take(NH * 2);
    u16* P1  = (u16*)take(NH * 2);
    u16* P2  = (u16*)take(NH * 2);
    u16* P3  = (u16*)take(NH * 2);

    const int AB = (EE + 4095) / 4096;          // 391 bucketing blocks
    const int NG = (NN + 255) / 256;
    const int PROP_GRID = 4 * ((NN + 3) / 4);   // 4 slices x 25000 node-blocks
    const int CB_GRID   = (NN + 63) / 64;
    const int S0_GRID   = (4 * NN + 255) / 256;

    // ---- CSR build via two-level bucketing
    hipMemsetAsync(gc, 0, 2 * NBUCK * 16 * 4, stream);
    bucketA_kernel <<<AB, 256, 0, stream>>>(src, dst, gcd, bregion);
    bucketA2_kernel<<<AB, 256, 0, stream>>>(src, gcs, sregion);
    bucketB_kernel <<<NBUCK, 256, 0, stream>>>(gcd, bregion, rstart, deg, colp);
    bucketB2_kernel<<<NBUCK, 256, 0, stream>>>(gcs, sregion, cs);
    dinv_kernel<<<NG, 256, 0, stream>>>(cs, dinv, ndsq, sdeg);
    fold_kernel<<<64, 256, 0, stream>>>(W1, bc1, g1, be1, rm1, rv1, Wfrag1, bf1);
    fold_kernel<<<64, 256, 0, stream>>>(W2, bc2, g2, be2, rm2, rv2, Wfrag2, bf2);
    fold_kernel<<<64, 256, 0, stream>>>(W3, bc3, g3, be3, rm3, rv3, Wfrag3, bf3);
    scale0_kernel<<<S0_GRID, 256, 0, stream>>>(x, dinv, Xhi, Xlo, P0);

    float* out16 = (float*)d_out;

    // ---- layer 1
    prop_kernel<<<PROP_GRID, 256, 0, stream>>>(P0, P1, rstart, deg, colp, ndsq);
    prop_kernel<<<PROP_GRID, 256, 0, stream>>>(P1, P2, rstart, deg, colp, ndsq);
    prop_kernel<<<PROP_GRID, 256, 0, stream>>>(P2, P3, rstart, deg, colp, ndsq);
    combine_kernel<false><<<CB_GRID, 256, 0, stream>>>(
        Xhi, Xlo, P1, P2, P3, sdeg, dinv, Wfrag1, bf1,
        Yhi, Ylo, P0, nullptr, nullptr, nullptr);
    // ---- layer 2
    prop_kernel<<<PROP_GRID, 256, 0, stream>>>(P0, P1, rstart, deg, colp, ndsq);
    prop_kernel<<<PROP_GRID, 256, 0, stream>>>(P1, P2, rstart, deg, colp, ndsq);
    prop_kernel<<<PROP_GRID, 256, 0, stream>>>(P2, P3, rstart, deg, colp, ndsq);
    combine_kernel<false><<<CB_GRID, 256, 0, stream>>>(
        Yhi, Ylo, P1, P2, P3, sdeg, dinv, Wfrag2, bf2,
        Xhi, Xlo, P0, nullptr, nullptr, nullptr);
    // ---- layer 3 (head fused)
    prop_kernel<<<PROP_GRID, 256, 0, stream>>>(P0, P1, rstart, deg, colp, ndsq);
    prop_kernel<<<PROP_GRID, 256, 0, stream>>>(P1, P2, rstart, deg, colp, ndsq);
    prop_kernel<<<PROP_GRID, 256, 0, stream>>>(P2, P3, rstart, deg, colp, ndsq);
    combine_kernel<true><<<CB_GRID, 256, 0, stream>>>(
        Xhi, Xlo, P1, P2, P3, sdeg, dinv, Wfrag3, bf3,
        nullptr, nullptr, nullptr, headW, headB, out16);
}

// Round 13
// 618.707 us; speedup vs baseline: 2.0306x; 2.0306x over previous
//
#include <hip/hip_runtime.h>

#define NN 100000
#define EE 1600000
#define HD 64
#define OCD 16
#define NBUCK 391          // ceil(NN/256)
#define CAP 5120           // per-bucket edge capacity (mean 4092, ~16 sigma margin)
#define BN_EPS 1e-5f

typedef unsigned short u16;
typedef unsigned int u32;
typedef unsigned long long u64;
typedef __attribute__((ext_vector_type(8))) short short8v;  // 8 bf16 (4 VGPR)
typedef __attribute__((ext_vector_type(4))) float f32x4;

union f32u32 { float f; unsigned int u; };

__device__ __forceinline__ float bflo(unsigned int u) {
    f32u32 c; c.u = u << 16; return c.f;
}
__device__ __forceinline__ float bfhi(unsigned int u) {
    f32u32 c; c.u = u & 0xffff0000u; return c.f;
}
__device__ __forceinline__ float bf2f(u16 u) {
    f32u32 c; c.u = (unsigned int)u << 16; return c.f;
}
__device__ __forceinline__ u16 f2bf(float f) {
    f32u32 c; c.f = f;
    unsigned int r = 0x7fffu + ((c.u >> 16) & 1u);   // RNE
    return (u16)((c.u + r) >> 16);
}

// ================================================================ bucket pass A (dst)
// packed entry: src (24b) | dst&255 (8b)  -- src < 2^24
__global__ __launch_bounds__(256) void bucketA_kernel(
        const int* __restrict__ src, const int* __restrict__ dst,
        int* __restrict__ gcd, u32* __restrict__ bregion) {
    __shared__ int lh[NBUCK], lbase[NBUCK], lcur[NBUCK];
    int t = threadIdx.x;
    int ebase = blockIdx.x * 4096;

    for (int i = t; i < NBUCK; i += 256) lh[i] = 0;
    __syncthreads();

    int es[16], ed[16];
    #pragma unroll
    for (int j = 0; j < 16; ++j) {
        int e = ebase + j * 256 + t;
        if (e < EE) {
            es[j] = src[e]; ed[j] = dst[e];
            atomicAdd(&lh[ed[j] >> 8], 1);
        } else { es[j] = -1; ed[j] = 0; }
    }
    __syncthreads();
    for (int i = t; i < NBUCK; i += 256) {
        int c = lh[i];
        lbase[i] = (c > 0) ? atomicAdd(&gcd[i * 16], c) : 0;
        lcur[i] = 0;
    }
    __syncthreads();
    #pragma unroll
    for (int j = 0; j < 16; ++j) {
        if (es[j] >= 0) {
            int b = ed[j] >> 8;
            int r = atomicAdd(&lcur[b], 1);
            int pos = lbase[b] + r;
            if (pos < CAP)
                bregion[(size_t)b * CAP + pos] =
                    (u32)es[j] | ((u32)(ed[j] & 255) << 24);
        }
    }
}

// bucket pass A2 (src, for out-degree)
__global__ __launch_bounds__(256) void bucketA2_kernel(
        const int* __restrict__ src,
        int* __restrict__ gcs, int* __restrict__ sregion) {
    __shared__ int lh[NBUCK], lbase[NBUCK], lcur[NBUCK];
    int t = threadIdx.x;
    int ebase = blockIdx.x * 4096;

    for (int i = t; i < NBUCK; i += 256) lh[i] = 0;
    __syncthreads();

    int es[16];
    #pragma unroll
    for (int j = 0; j < 16; ++j) {
        int e = ebase + j * 256 + t;
        if (e < EE) {
            es[j] = src[e];
            atomicAdd(&lh[es[j] >> 8], 1);
        } else es[j] = -1;
    }
    __syncthreads();
    for (int i = t; i < NBUCK; i += 256) {
        int c = lh[i];
        lbase[i] = (c > 0) ? atomicAdd(&gcs[i * 16], c) : 0;
        lcur[i] = 0;
    }
    __syncthreads();
    #pragma unroll
    for (int j = 0; j < 16; ++j) {
        if (es[j] >= 0) {
            int b = es[j] >> 8;
            int r = atomicAdd(&lcur[b], 1);
            int pos = lbase[b] + r;
            if (pos < CAP)
                sregion[(size_t)b * CAP + pos] = es[j];
        }
    }
}

// pass B: per dst-bucket CSR
__global__ __launch_bounds__(256) void bucketB_kernel(
        const int* __restrict__ gcd, const u32* __restrict__ bregion,
        int* __restrict__ rstart, int* __restrict__ deg,
        int* __restrict__ colp) {
    __shared__ int lh[256], lsc[256], lcur[256];
    int b = blockIdx.x, t = threadIdx.x;
    int cnt = min(gcd[b * 16], CAP);
    size_t base = (size_t)b * CAP;

    lh[t] = 0;
    __syncthreads();
    for (int i = t; i < cnt; i += 256)
        atomicAdd(&lh[bregion[base + i] >> 24], 1);
    __syncthreads();
    lsc[t] = lh[t];
    __syncthreads();
    for (int o = 1; o < 256; o <<= 1) {
        int v = (t >= o) ? lsc[t - o] : 0;
        __syncthreads();
        lsc[t] += v;
        __syncthreads();
    }
    int excl = lsc[t] - lh[t];
    int node = b * 256 + t;
    if (node < NN) {
        rstart[node] = (int)base + excl;
        deg[node] = lh[t];
    }
    lcur[t] = excl;
    __syncthreads();
    for (int i = t; i < cnt; i += 256) {
        u32 pair = bregion[base + i];
        int s = (int)(pair & 0xffffffu);
        int dl = (int)(pair >> 24);
        int p = atomicAdd(&lcur[dl], 1);
        colp[base + p] = s;
    }
}

// per src-bucket: out-degree -> cs
__global__ __launch_bounds__(256) void bucketB2_kernel(
        const int* __restrict__ gcs, const int* __restrict__ sregion,
        int* __restrict__ cs) {
    __shared__ int lh[256];
    int b = blockIdx.x, t = threadIdx.x;
    int cnt = min(gcs[b * 16], CAP);
    size_t base = (size_t)b * CAP;

    lh[t] = 0;
    __syncthreads();
    for (int i = t; i < cnt; i += 256)
        atomicAdd(&lh[sregion[base + i] & 255], 1);
    __syncthreads();
    int node = b * 256 + t;
    if (node < NN) cs[node] = lh[t];
}

__global__ void dinv_kernel(const int* __restrict__ cs, float* __restrict__ dinv,
                            float* __restrict__ ndsq, float* __restrict__ sdeg) {
    int i = blockIdx.x * 256 + threadIdx.x;
    if (i < NN) {
        int d = cs[i];
        float di = (d > 0) ? rsqrtf((float)d) : 0.0f;
        dinv[i] = di;
        ndsq[i] = -di * di;
        sdeg[i] = (d > 0) ? sqrtf((float)d) : 0.0f;
    }
}

// ================================================================ weight fold + MFMA-fragment repack
__global__ void fold_kernel(const float* __restrict__ W, const float* __restrict__ bc,
                            const float* __restrict__ g, const float* __restrict__ be,
                            const float* __restrict__ rm, const float* __restrict__ rv,
                            u16* __restrict__ Wfrag, float* __restrict__ biasf) {
    int idx = blockIdx.x * 256 + threadIdx.x;
    if (idx >= 16384) return;
    int km = idx >> 12, r = idx & 4095, i = r >> 6, h = r & 63;
    float sc = g[h] * rsqrtf(rv[h] + BN_EPS);
    int e = i * 64 + h;
    float wv;
    if      (km == 0) wv = (W[e] - W[8192 + e]) * sc;
    else if (km == 1) wv = (W[4096 + e] - 3.0f * W[12288 + e]) * sc;
    else if (km == 2) wv = 2.0f * W[8192 + e] * sc;
    else              wv = 4.0f * W[12288 + e] * sc;
    u16 hi = f2bf(wv);
    u16 lo = f2bf(wv - bf2f(hi));
    int lane = (((i & 31) >> 3) << 4) | (h & 15);
    int base = (km * 2) * 4096 + (i >> 5) * 2048 + (h >> 4) * 512 + lane * 8 + (i & 7);
    Wfrag[base] = hi;
    Wfrag[base + 4096] = lo;
    if (idx < 64)
        biasf[idx] = (bc[idx] - rm[idx]) * g[idx] * rsqrtf(rv[idx] + BN_EPS) + be[idx];
}

// ================================================================ x -> Xhi/Xlo + P0
__global__ void scale0_kernel(const float* __restrict__ x, const float* __restrict__ dinv,
                              u16* __restrict__ Xhi, u16* __restrict__ Xlo,
                              u16* __restrict__ P0) {
    int idx = blockIdx.x * 256 + threadIdx.x;       // one float4 per thread
    if (idx >= NN * (HD / 4)) return;
    int n = idx >> 4;
    float di = dinv[n];
    float4 v = ((const float4*)x)[idx];
    float vv[4] = {v.x, v.y, v.z, v.w};
    u16 hi[4], lo[4], p[4];
    #pragma unroll
    for (int j = 0; j < 4; ++j) {
        hi[j] = f2bf(vv[j]);
        lo[j] = f2bf(vv[j] - bf2f(hi[j]));
        p[j]  = f2bf(di * vv[j]);
    }
    *(u64*)(&Xhi[(size_t)idx * 4]) = *(u64*)hi;
    *(u64*)(&Xlo[(size_t)idx * 4]) = *(u64*)lo;
    *(u64*)(&P0 [(size_t)idx * 4]) = *(u64*)p;
}

// ================================================================ propagation (round-10 form)
__global__ __launch_bounds__(256) void prop_kernel(
        const u16* __restrict__ Pin, u16* __restrict__ Pout,
        const int* __restrict__ rstart, const int* __restrict__ deg,
        const int* __restrict__ col, const float* __restrict__ ndsq) {
    int d = blockIdx.x * 4 + (threadIdx.x >> 6);
    if (d >= NN) return;
    int lane = threadIdx.x & 63;
    int g = lane >> 4;        // 0..3  edge slot
    int l = lane & 15;        // 0..15 feature quad
    int e0 = rstart[d], e1 = e0 + deg[d];

    float a0 = 0.f, a1 = 0.f, a2 = 0.f, a3 = 0.f;
    int e = e0 + g;
    for (; e + 4 < e1; e += 8) {
        int s0 = col[e], s1 = col[e + 4];
        uint2 u0 = *(const uint2*)(Pin + (size_t)s0 * HD + l * 4);
        uint2 u1 = *(const uint2*)(Pin + (size_t)s1 * HD + l * 4);
        a0 += bflo(u0.x); a1 += bfhi(u0.x);
        a2 += bflo(u0.y); a3 += bfhi(u0.y);
        a0 += bflo(u1.x); a1 += bfhi(u1.x);
        a2 += bflo(u1.y); a3 += bfhi(u1.y);
    }
    if (e < e1) {
        int s = col[e];
        uint2 u = *(const uint2*)(Pin + (size_t)s * HD + l * 4);
        a0 += bflo(u.x); a1 += bfhi(u.x);
        a2 += bflo(u.y); a3 += bfhi(u.y);
    }
    a0 += __shfl_xor(a0, 16); a1 += __shfl_xor(a1, 16);
    a2 += __shfl_xor(a2, 16); a3 += __shfl_xor(a3, 16);
    a0 += __shfl_xor(a0, 32); a1 += __shfl_xor(a1, 32);
    a2 += __shfl_xor(a2, 32); a3 += __shfl_xor(a3, 32);

    if (g == 0) {
        float nd = ndsq[d];
        uint2 o;
        o.x = (unsigned int)f2bf(nd * a0) | ((unsigned int)f2bf(nd * a1) << 16);
        o.y = (unsigned int)f2bf(nd * a2) | ((unsigned int)f2bf(nd * a3) << 16);
        *(uint2*)(Pout + (size_t)d * HD + l * 4) = o;
    }
}

// ================================================================ MFMA combine (round-10 form)
template<bool FUSE_HEAD>
__global__ __launch_bounds__(256) void combine_kernel(
        const u16* __restrict__ Xhi, const u16* __restrict__ Xlo,
        const u16* __restrict__ P1, const u16* __restrict__ P2,
        const u16* __restrict__ P3,
        const float* __restrict__ sdeg, const float* __restrict__ dinv,
        const u16* __restrict__ Wfrag, const float* __restrict__ biasf,
        u16* __restrict__ outDhi, u16* __restrict__ outDlo, u16* __restrict__ outP0,
        const float* __restrict__ headW, const float* __restrict__ headB,
        float* __restrict__ out16) {
    int t = threadIdx.x;
    int w = t >> 6;           // m-tile
    int l = t & 63;
    int nbase = blockIdx.x * 64;

    int arow = nbase + w * 16 + (l & 15);
    if (arow > NN - 1) arow = NN - 1;            // tail clamp (stores guarded)
    size_t abase = (size_t)arow * HD;

    f32x4 accX[4], accP[4];
    #pragma unroll
    for (int nt = 0; nt < 4; ++nt) {
        accX[nt] = (f32x4){0.f, 0.f, 0.f, 0.f};
        accP[nt] = (f32x4){0.f, 0.f, 0.f, 0.f};
    }

    #pragma unroll
    for (int ks = 0; ks < 2; ++ks) {
        size_t ao = abase + ks * 32 + (l >> 4) * 8;
        short8v aXhi = *(const short8v*)(Xhi + ao);
        short8v aXlo = *(const short8v*)(Xlo + ao);
        short8v aP1  = *(const short8v*)(P1  + ao);
        short8v aP2  = *(const short8v*)(P2  + ao);
        short8v aP3  = *(const short8v*)(P3  + ao);
        #pragma unroll
        for (int nt = 0; nt < 4; ++nt) {
            const u16* wb = Wfrag + ks * 2048 + nt * 512 + l * 8;
            short8v b0h = *(const short8v*)(wb);            // km0 hi
            short8v b0l = *(const short8v*)(wb + 4096);     // km0 lo
            short8v b1h = *(const short8v*)(wb + 8192);
            short8v b1l = *(const short8v*)(wb + 12288);
            short8v b2h = *(const short8v*)(wb + 16384);
            short8v b2l = *(const short8v*)(wb + 20480);
            short8v b3h = *(const short8v*)(wb + 24576);
            short8v b3l = *(const short8v*)(wb + 28672);
            accX[nt] = __builtin_amdgcn_mfma_f32_16x16x32_bf16(aXhi, b0h, accX[nt], 0, 0, 0);
            accX[nt] = __builtin_amdgcn_mfma_f32_16x16x32_bf16(aXlo, b0h, accX[nt], 0, 0, 0);
            accX[nt] = __builtin_amdgcn_mfma_f32_16x16x32_bf16(aXhi, b0l, accX[nt], 0, 0, 0);
            accP[nt] = __builtin_amdgcn_mfma_f32_16x16x32_bf16(aP1,  b1h, accP[nt], 0, 0, 0);
            accP[nt] = __builtin_amdgcn_mfma_f32_16x16x32_bf16(aP1,  b1l, accP[nt], 0, 0, 0);
            accP[nt] = __builtin_amdgcn_mfma_f32_16x16x32_bf16(aP2,  b2h, accP[nt], 0, 0, 0);
            accP[nt] = __builtin_amdgcn_mfma_f32_16x16x32_bf16(aP2,  b2l, accP[nt], 0, 0, 0);
            accP[nt] = __builtin_amdgcn_mfma_f32_16x16x32_bf16(aP3,  b3h, accP[nt], 0, 0, 0);
            accP[nt] = __builtin_amdgcn_mfma_f32_16x16x32_bf16(aP3,  b3l, accP[nt], 0, 0, 0);
        }
    }

    // epilogue: C/D layout col=lane&15, row=(lane>>4)*4+reg  [m89 verified]
    int col = l & 15;
    int rbase = w * 16 + (l >> 4) * 4;

    if (!FUSE_HEAD) {
        #pragma unroll
        for (int nt = 0; nt < 4; ++nt) {
            int h = nt * 16 + col;
            float bi = biasf[h];
            #pragma unroll
            for (int reg = 0; reg < 4; ++reg) {
                int node = nbase + rbase + reg;
                int nodeL = node > NN - 1 ? NN - 1 : node;
                float val = accX[nt][reg] + sdeg[nodeL] * accP[nt][reg] + bi;
                val = fmaxf(val, 0.f);
                if (node < NN) {
                    u16 hi = f2bf(val);
                    size_t o = (size_t)node * HD + h;
                    outDhi[o] = hi;
                    outDlo[o] = f2bf(val - bf2f(hi));
                    outP0[o]  = f2bf(dinv[nodeL] * val);
                }
            }
        }
    } else {
        __shared__ float Tl[64][68];
        __shared__ float Wl[HD * OCD];
        #pragma unroll
        for (int nt = 0; nt < 4; ++nt) {
            int h = nt * 16 + col;
            float bi = biasf[h];
            #pragma unroll
            for (int reg = 0; reg < 4; ++reg) {
                int node = nbase + rbase + reg;
                int nodeL = node > NN - 1 ? NN - 1 : node;
                float val = accX[nt][reg] + sdeg[nodeL] * accP[nt][reg] + bi;
                Tl[rbase + reg][h] = fmaxf(val, 0.f);
            }
        }
        ((float4*)Wl)[t & 255] = ((const float4*)headW)[t & 255];  // 1024 floats
        __syncthreads();

        int n = t >> 2;
        int oc0 = (t & 3) * 4;
        float4 o;
        o.x = headB[oc0]; o.y = headB[oc0 + 1]; o.z = headB[oc0 + 2]; o.w = headB[oc0 + 3];
        #pragma unroll 8
        for (int i = 0; i < 64; ++i) {
            float tv = Tl[n][i];
            const float* wr = &Wl[i * OCD + oc0];
            o.x = fmaf(tv, wr[0], o.x);
            o.y = fmaf(tv, wr[1], o.y);
            o.z = fmaf(tv, wr[2], o.z);
            o.w = fmaf(tv, wr[3], o.w);
        }
        int nn = nbase + n;
        if (nn < NN) *(float4*)(&out16[(size_t)nn * OCD + oc0]) = o;
    }
}

// ================================================================ launch
static inline size_t al256(size_t x) { return (x + 255) & ~(size_t)255; }

extern "C" void kernel_launch(void* const* d_in, const int* in_sizes, int n_in,
                              void* d_out, int out_size, void* d_ws, size_t ws_size,
                              hipStream_t stream) {
    const float* x     = (const float*)d_in[0];
    const int*   ei    = (const int*)  d_in[1];
    const float* W1    = (const float*)d_in[2];
    const float* bc1   = (const float*)d_in[3];
    const float* W2    = (const float*)d_in[4];
    const float* bc2   = (const float*)d_in[5];
    const float* W3    = (const float*)d_in[6];
    const float* bc3   = (const float*)d_in[7];
    const float* g1  = (const float*)d_in[8],  *be1 = (const float*)d_in[9];
    const float* rm1 = (const float*)d_in[10], *rv1 = (const float*)d_in[11];
    const float* g2  = (const float*)d_in[12], *be2 = (const float*)d_in[13];
    const float* rm2 = (const float*)d_in[14], *rv2 = (const float*)d_in[15];
    const float* g3  = (const float*)d_in[16], *be3 = (const float*)d_in[17];
    const float* rm3 = (const float*)d_in[18], *rv3 = (const float*)d_in[19];
    const float* headW = (const float*)d_in[20];
    const float* headB = (const float*)d_in[21];

    const int* src = ei;
    const int* dst = ei + EE;

    char* w = (char*)d_ws;
    size_t off = 0;
    auto take = [&](size_t bytes) { char* p = w + off; off += al256(bytes); return p; };
    float* dinv   = (float*)take(NN * 4);
    float* ndsq   = (float*)take(NN * 4);
    float* sdeg   = (float*)take(NN * 4);
    int*   cs     = (int*)  take(NN * 4);
    int*   deg    = (int*)  take(NN * 4);
    int*   rstart = (int*)  take(NN * 4);
    int*   gc     = (int*)  take(2 * NBUCK * 16 * 4);        // gcd | gcs contiguous
    int*   gcd    = gc;
    int*   gcs    = gc + NBUCK * 16;
    u32*   bregion= (u32*)  take((size_t)NBUCK * CAP * 4);   //  8.0 MB (packed u32)
    int*   sregion= (int*)  take((size_t)NBUCK * CAP * 4);   //  8.0 MB
    int*   colp   = (int*)  take((size_t)NBUCK * CAP * 4);   //  8.0 MB
    u16*   Wfrag1 = (u16*)  take(32768 * 2);                 // 64 KB each
    u16*   Wfrag2 = (u16*)  take(32768 * 2);
    u16*   Wfrag3 = (u16*)  take(32768 * 2);
    float* bf1    = (float*)take(64 * 4);
    float* bf2    = (float*)take(64 * 4);
    float* bf3    = (float*)take(64 * 4);
    const size_t NH = (size_t)NN * HD;
    u16* Xhi = (u16*)take(NH * 2);
    u16* Xlo = (u16*)take(NH * 2);
    u16* Yhi = (u16*)take(NH * 2);
    u16* Ylo = (u16*)take(NH * 2);
    u16* P0  = (u16*)take(NH * 2);
    u16* P1  = (u16*)take(NH * 2);
    u16* P2  = (u16*)take(NH * 2);
    u16* P3  = (u16*)take(NH * 2);

    const int AB = (EE + 4095) / 4096;          // 391 bucketing blocks
    const int NG = (NN + 255) / 256;
    const int PROP_GRID = (NN + 3) / 4;
    const int CB_GRID   = (NN + 63) / 64;
    const int S0_GRID   = (NN * (HD / 4) + 255) / 256;

    // ---- CSR build via two-level bucketing
    hipMemsetAsync(gc, 0, 2 * NBUCK * 16 * 4, stream);
    bucketA_kernel <<<AB, 256, 0, stream>>>(src, dst, gcd, bregion);
    bucketA2_kernel<<<AB, 256, 0, stream>>>(src, gcs, sregion);
    bucketB_kernel <<<NBUCK, 256, 0, stream>>>(gcd, bregion, rstart, deg, colp);
    bucketB2_kernel<<<NBUCK, 256, 0, stream>>>(gcs, sregion, cs);
    dinv_kernel<<<NG, 256, 0, stream>>>(cs, dinv, ndsq, sdeg);
    fold_kernel<<<64, 256, 0, stream>>>(W1, bc1, g1, be1, rm1, rv1, Wfrag1, bf1);
    fold_kernel<<<64, 256, 0, stream>>>(W2, bc2, g2, be2, rm2, rv2, Wfrag2, bf2);
    fold_kernel<<<64, 256, 0, stream>>>(W3, bc3, g3, be3, rm3, rv3, Wfrag3, bf3);
    scale0_kernel<<<S0_GRID, 256, 0, stream>>>(x, dinv, Xhi, Xlo, P0);

    float* out16 = (float*)d_out;

    // ---- layer 1
    prop_kernel<<<PROP_GRID, 256, 0, stream>>>(P0, P1, rstart, deg, colp, ndsq);
    prop_kernel<<<PROP_GRID, 256, 0, stream>>>(P1, P2, rstart, deg, colp, ndsq);
    prop_kernel<<<PROP_GRID, 256, 0, stream>>>(P2, P3, rstart, deg, colp, ndsq);
    combine_kernel<false><<<CB_GRID, 256, 0, stream>>>(
        Xhi, Xlo, P1, P2, P3, sdeg, dinv, Wfrag1, bf1,
        Yhi, Ylo, P0, nullptr, nullptr, nullptr);
    // ---- layer 2
    prop_kernel<<<PROP_GRID, 256, 0, stream>>>(P0, P1, rstart, deg, colp, ndsq);
    prop_kernel<<<PROP_GRID, 256, 0, stream>>>(P1, P2, rstart, deg, colp, ndsq);
    prop_kernel<<<PROP_GRID, 256, 0, stream>>>(P2, P3, rstart, deg, colp, ndsq);
    combine_kernel<false><<<CB_GRID, 256, 0, stream>>>(
        Yhi, Ylo, P1, P2, P3, sdeg, dinv, Wfrag2, bf2,
        Xhi, Xlo, P0, nullptr, nullptr, nullptr);
    // ---- layer 3 (head fused)
    prop_kernel<<<PROP_GRID, 256, 0, stream>>>(P0, P1, rstart, deg, colp, ndsq);
    prop_kernel<<<PROP_GRID, 256, 0, stream>>>(P1, P2, rstart, deg, colp, ndsq);
    prop_kernel<<<PROP_GRID, 256, 0, stream>>>(P2, P3, rstart, deg, colp, ndsq);
    combine_kernel<true><<<CB_GRID, 256, 0, stream>>>(
        Xhi, Xlo, P1, P2, P3, sdeg, dinv, Wfrag3, bf3,
        nullptr, nullptr, nullptr, headW, headB, out16);
}